// Round 10
// baseline (246.894 us; speedup 1.0000x reference)
//
#include <hip/hip_runtime.h>

#define KCODES 512
#define DIM 64
#define NB 32
#define NH 64
#define NW 64
#define NPTS (NB*NH*NW)     // 131072
#define HW (NH*NW)          // 4096

// ---- output layout (floats) ----
#define O_OUT  0
#define O_LOSS 8388608
#define O_IDX  8388609
#define O_EMB  8519681
#define O_M    8552449
#define O_MM   8585217

// ---- workspace layout (floats) ----
#define W_DM   0
#define W_CNT  (KCODES*DIM)         // 32768
#define W_LOSS (W_CNT + KCODES)     // 33280
#define W_NEWM (W_LOSS + 1)         // 33281
#define W_C    (W_NEWM + KCODES)    // 33793
#define W_TOTAL (W_C + KCODES)      // 34305

#define XSTR 72   // bf16 row stride: 144B -> frag reads land 2-way on bank quads (free)
#define EPS_GAP 0.0625f

using bfrag = __attribute__((ext_vector_type(8))) short;
using f32x4 = __attribute__((ext_vector_type(4))) float;

__device__ __forceinline__ unsigned short f2bh(float x) {   // RNE fp32->bf16
    unsigned u = __float_as_uint(x);
    return (unsigned short)((u + 0x7FFFu + ((u >> 16) & 1u)) >> 16);
}
__device__ __forceinline__ float bf2f(unsigned short h) {
    return __uint_as_float(((unsigned)h) << 16);
}

__global__ void cnorm_kernel(const float* __restrict__ emb, float* __restrict__ ws) {
    int k = blockIdx.x * blockDim.x + threadIdx.x;
    if (k >= KCODES) return;
    float s = 0.f;
    #pragma unroll
    for (int d = 0; d < DIM; ++d) { float v = emb[k*DIM + d]; s += v*v; }
    ws[W_C + k] = s;
}

// Split-bf16 MFMA assign: dot = xh.eh + xh.el + xl.eh (xl.el ~2^-18 dropped).
// Tracks (best, idx, second-best); gap < EPS -> exact fp32 block rescue, so
// argmin == fp32 argmin for every point (counts stay exact).
__global__ __launch_bounds__(256, 2) void assign_kernel(
    const float* __restrict__ enc, const float* __restrict__ emb,
    float* __restrict__ out, float* __restrict__ ws)
{
    __shared__ unsigned short XH[128*XSTR], XLo[128*XSTR];   // [point][d]
    __shared__ unsigned short EH[128*XSTR], ELo[128*XSTR];   // [cw][d] per tile
    __shared__ float cnT[128];
    __shared__ int   bestI[128];
    __shared__ float gapL[128];
    __shared__ float rsS[4]; __shared__ int rsK[4];

    const int t  = threadIdx.x;
    const int l  = t & 63;
    const int wv = t >> 6;
    const int R0 = blockIdx.x * 2;

    // ---- stage X as hi/lo bf16 (coalesced strided loads, as r9) ----
    #pragma unroll
    for (int r2 = 0; r2 < 2; ++r2) {
        int R = R0 + r2, b = R >> 6, h = R & 63;
        const float* base = enc + (size_t)b*64*HW + (size_t)h*64 + (t & 63);
        int p = r2*64 + (t & 63);
        #pragma unroll
        for (int it = 0; it < 4; ++it) {
            int d0 = (it*4 + wv)*4;
            float4 v = make_float4(base[(size_t)(d0+0)*HW], base[(size_t)(d0+1)*HW],
                                   base[(size_t)(d0+2)*HW], base[(size_t)(d0+3)*HW]);
            unsigned short h0=f2bh(v.x), h1=f2bh(v.y), h2=f2bh(v.z), h3=f2bh(v.w);
            float4 lo = make_float4(v.x-bf2f(h0), v.y-bf2f(h1), v.z-bf2f(h2), v.w-bf2f(h3));
            unsigned short g0=f2bh(lo.x), g1=f2bh(lo.y), g2=f2bh(lo.z), g3=f2bh(lo.w);
            *(uint2*)&XH [p*XSTR + d0] = make_uint2((unsigned)h0|((unsigned)h1<<16),
                                                    (unsigned)h2|((unsigned)h3<<16));
            *(uint2*)&XLo[p*XSTR + d0] = make_uint2((unsigned)g0|((unsigned)g1<<16),
                                                    (unsigned)g2|((unsigned)g3<<16));
        }
    }
    __syncthreads();

    // ---- A-fragments: row=l&15, k=(l>>4)*8+j ; held across all tiles ----
    const int row16 = l & 15, kgrp = l >> 4;
    const int mtA = wv*2, mtB = wv*2 + 1;    // wave owns 2 M-tiles
    bfrag ah00 = *(bfrag*)&XH [(mtA*16+row16)*XSTR +  0 + kgrp*8];
    bfrag ah01 = *(bfrag*)&XH [(mtA*16+row16)*XSTR + 32 + kgrp*8];
    bfrag ah10 = *(bfrag*)&XH [(mtB*16+row16)*XSTR +  0 + kgrp*8];
    bfrag ah11 = *(bfrag*)&XH [(mtB*16+row16)*XSTR + 32 + kgrp*8];
    bfrag al00 = *(bfrag*)&XLo[(mtA*16+row16)*XSTR +  0 + kgrp*8];
    bfrag al01 = *(bfrag*)&XLo[(mtA*16+row16)*XSTR + 32 + kgrp*8];
    bfrag al10 = *(bfrag*)&XLo[(mtB*16+row16)*XSTR +  0 + kgrp*8];
    bfrag al11 = *(bfrag*)&XLo[(mtB*16+row16)*XSTR + 32 + kgrp*8];

    float b1[2][4], b2[2][4]; int k1[2][4];
    #pragma unroll
    for (int mi = 0; mi < 2; ++mi)
        #pragma unroll
        for (int r = 0; r < 4; ++r) { b1[mi][r] = 3.402823466e38f; b2[mi][r] = 3.402823466e38f; k1[mi][r] = 0; }

    for (int tile = 0; tile < 4; ++tile) {
        __syncthreads();
        const float* esrc = emb + (size_t)tile*128*64;
        #pragma unroll
        for (int it = 0; it < 8; ++it) {
            int idx = t + it*256;
            int er = idx >> 4, ec = (idx & 15)*4;
            float4 v = *(const float4*)(esrc + er*64 + ec);
            unsigned short h0=f2bh(v.x), h1=f2bh(v.y), h2=f2bh(v.z), h3=f2bh(v.w);
            float4 lo = make_float4(v.x-bf2f(h0), v.y-bf2f(h1), v.z-bf2f(h2), v.w-bf2f(h3));
            unsigned short g0=f2bh(lo.x), g1=f2bh(lo.y), g2=f2bh(lo.z), g3=f2bh(lo.w);
            *(uint2*)&EH [er*XSTR + ec] = make_uint2((unsigned)h0|((unsigned)h1<<16),
                                                     (unsigned)h2|((unsigned)h3<<16));
            *(uint2*)&ELo[er*XSTR + ec] = make_uint2((unsigned)g0|((unsigned)g1<<16),
                                                     (unsigned)g2|((unsigned)g3<<16));
        }
        if (t < 128) cnT[t] = ws[W_C + tile*128 + t];
        __syncthreads();

        for (int nt = 0; nt < 8; ++nt) {
            bfrag bh0 = *(bfrag*)&EH [(nt*16+row16)*XSTR +  0 + kgrp*8];
            bfrag bh1 = *(bfrag*)&EH [(nt*16+row16)*XSTR + 32 + kgrp*8];
            bfrag bl0 = *(bfrag*)&ELo[(nt*16+row16)*XSTR +  0 + kgrp*8];
            bfrag bl1 = *(bfrag*)&ELo[(nt*16+row16)*XSTR + 32 + kgrp*8];
            float cnv = cnT[nt*16 + row16];
            int kcol = tile*128 + nt*16 + row16;

            f32x4 acc = {0.f, 0.f, 0.f, 0.f};
            acc = __builtin_amdgcn_mfma_f32_16x16x32_bf16(ah00, bh0, acc, 0,0,0);
            acc = __builtin_amdgcn_mfma_f32_16x16x32_bf16(ah01, bh1, acc, 0,0,0);
            acc = __builtin_amdgcn_mfma_f32_16x16x32_bf16(ah00, bl0, acc, 0,0,0);
            acc = __builtin_amdgcn_mfma_f32_16x16x32_bf16(ah01, bl1, acc, 0,0,0);
            acc = __builtin_amdgcn_mfma_f32_16x16x32_bf16(al00, bh0, acc, 0,0,0);
            acc = __builtin_amdgcn_mfma_f32_16x16x32_bf16(al01, bh1, acc, 0,0,0);
            #pragma unroll
            for (int r = 0; r < 4; ++r) {
                float s = fmaf(-2.f, acc[r], cnv);
                if (s < b1[0][r]) { b2[0][r] = b1[0][r]; b1[0][r] = s; k1[0][r] = kcol; }
                else if (s < b2[0][r]) b2[0][r] = s;
            }
            f32x4 ac2 = {0.f, 0.f, 0.f, 0.f};
            ac2 = __builtin_amdgcn_mfma_f32_16x16x32_bf16(ah10, bh0, ac2, 0,0,0);
            ac2 = __builtin_amdgcn_mfma_f32_16x16x32_bf16(ah11, bh1, ac2, 0,0,0);
            ac2 = __builtin_amdgcn_mfma_f32_16x16x32_bf16(ah10, bl0, ac2, 0,0,0);
            ac2 = __builtin_amdgcn_mfma_f32_16x16x32_bf16(ah11, bl1, ac2, 0,0,0);
            ac2 = __builtin_amdgcn_mfma_f32_16x16x32_bf16(al10, bh0, ac2, 0,0,0);
            ac2 = __builtin_amdgcn_mfma_f32_16x16x32_bf16(al11, bh1, ac2, 0,0,0);
            #pragma unroll
            for (int r = 0; r < 4; ++r) {
                float s = fmaf(-2.f, ac2[r], cnv);
                if (s < b1[1][r]) { b2[1][r] = b1[1][r]; b1[1][r] = s; k1[1][r] = kcol; }
                else if (s < b2[1][r]) b2[1][r] = s;
            }
        }
    }

    // ---- cross-lane (16 col-lanes) argmin with second-best tracking ----
    #pragma unroll
    for (int mi = 0; mi < 2; ++mi)
        #pragma unroll
        for (int r = 0; r < 4; ++r) {
            float b = b1[mi][r], c2 = b2[mi][r]; int kk = k1[mi][r];
            #pragma unroll
            for (int off = 1; off < 16; off <<= 1) {
                float ob  = __shfl_xor(b,  off, 64);
                int   ok  = __shfl_xor(kk, off, 64);
                float oc2 = __shfl_xor(c2, off, 64);
                bool win = (ob < b) || (ob == b && ok < kk);
                if (win) { c2 = fminf(b, oc2); b = ob; kk = ok; }
                else     { c2 = fminf(c2, ob); }
            }
            if (row16 == 0) {
                int p = (wv*2 + mi)*16 + kgrp*4 + r;
                bestI[p] = kk; gapL[p] = c2 - b;
            }
        }
    __syncthreads();

    // ---- exact fp32 rescue for near-ties (block-uniform control flow) ----
    for (int p = 0; p < 128; ++p) {
        if (gapL[p] >= EPS_GAP) continue;
        const int P = R0*64 + p;
        const float* xb = enc + ((size_t)(P >> 12))*(64*HW)
                              + ((size_t)((P >> 6) & 63))*64 + (P & 63);
        const float* e0 = emb + t*64;
        const float* e1 = emb + (t+256)*64;
        float dot0 = 0.f, dot1 = 0.f;
        #pragma unroll
        for (int d4 = 0; d4 < 16; ++d4) {
            float4 ev0 = *(const float4*)(e0 + d4*4);
            float4 ev1 = *(const float4*)(e1 + d4*4);
            float x0 = xb[(size_t)(d4*4+0)*HW], x1 = xb[(size_t)(d4*4+1)*HW];
            float x2 = xb[(size_t)(d4*4+2)*HW], x3 = xb[(size_t)(d4*4+3)*HW];
            dot0 = fmaf(x0,ev0.x,fmaf(x1,ev0.y,fmaf(x2,ev0.z,fmaf(x3,ev0.w,dot0))));
            dot1 = fmaf(x0,ev1.x,fmaf(x1,ev1.y,fmaf(x2,ev1.z,fmaf(x3,ev1.w,dot1))));
        }
        float s0 = ws[W_C + t]       - 2.f*dot0;
        float s1 = ws[W_C + t + 256] - 2.f*dot1;
        float sb; int kb;
        if (s0 <= s1) { sb = s0; kb = t; } else { sb = s1; kb = t + 256; }
        #pragma unroll
        for (int off = 1; off < 64; off <<= 1) {
            float ob = __shfl_xor(sb, off, 64);
            int   ok = __shfl_xor(kb, off, 64);
            if (ob < sb || (ob == sb && ok < kb)) { sb = ob; kb = ok; }
        }
        if (l == 0) { rsS[wv] = sb; rsK[wv] = kb; }
        __syncthreads();
        if (t == 0) {
            float bb = rsS[0]; int bk = rsK[0];
            #pragma unroll
            for (int v = 1; v < 4; ++v)
                if (rsS[v] < bb || (rsS[v] == bb && rsK[v] < bk)) { bb = rsS[v]; bk = rsK[v]; }
            bestI[p] = bk;
        }
        __syncthreads();
    }

    if (t < 128) out[O_IDX + (size_t)R0*64 + t] = (float)bestI[t];
}

// unchanged from r9: fused dm/cnt LDS accumulation + quantized store + loss
__global__ __launch_bounds__(512, 1) void scatter_kernel(
    const float* __restrict__ enc, const float* __restrict__ emb,
    float* __restrict__ out, float* __restrict__ ws)
{
    __shared__ float dmL[KCODES][DIM+1];
    __shared__ float cntL[KCODES];
    __shared__ float redL[8];

    const int t  = threadIdx.x;
    const int w  = t & 63;
    const int wv = t >> 6;
    const int pg = w >> 4, dl = w & 15;

    float* dmf = &dmL[0][0];
    for (int i = t; i < KCODES*(DIM+1); i += 512) dmf[i] = 0.f;
    if (t < KCODES) cntL[t] = 0.f;
    __syncthreads();

    const int R = blockIdx.x * 8 + wv;
    const int b = R >> 6, h = R & 63;
    const float* base  = enc + (size_t)b*(64*HW) + (size_t)h*64;
    float*       obase = out + O_OUT + (size_t)b*(64*HW) + (size_t)h*64;

    const int bidx = (int)out[O_IDX + (size_t)R*64 + w];
    atomicAdd(&cntL[bidx], 1.0f);
    float lsum = 0.f;

    #pragma unroll
    for (int c = 0; c < 4; ++c) {
        #pragma unroll
        for (int jj = 0; jj < 16; ++jj) {
            int p  = jj*4 + pg;
            int kb = __shfl(bidx, p, 64);
            int d  = c*16 + dl;
            float xv = base[(size_t)d*HW + p];
            atomicAdd(&dmL[kb][d], xv);
            float q = emb[kb*64 + d];
            obase[(size_t)d*HW + p] = q;
            float df = q - xv;
            lsum = fmaf(df, df, lsum);
        }
    }

    #pragma unroll
    for (int off = 32; off >= 1; off >>= 1) lsum += __shfl_down(lsum, off, 64);
    if (w == 0) redL[wv] = lsum;
    __syncthreads();
    if (t == 0) {
        float s = 0.f;
        #pragma unroll
        for (int v = 0; v < 8; ++v) s += redL[v];
        atomicAdd(&ws[W_LOSS], s);
    }

    for (int k = wv*64; k < wv*64 + 64; ++k) {
        float c = cntL[k];
        if (c == 0.f) continue;
        atomicAdd(&ws[W_DM + k*64 + w], dmL[k][w]);
        if (w == 0) atomicAdd(&ws[W_CNT + k], c);
    }
}

__global__ void finalizeA(const float* __restrict__ emaM,
                          float* __restrict__ out, float* __restrict__ ws)
{
    __shared__ float red[512];
    int k = threadIdx.x;
    float nM = 0.99f * emaM[k] + 0.01f * ws[W_CNT + k];
    red[k] = nM;
    __syncthreads();
    for (int s = 256; s >= 1; s >>= 1) {
        if (k < s) red[k] += red[k + s];
        __syncthreads();
    }
    float Ntot = red[0];
    float sm = (nM + 1e-5f) / (Ntot + 1e-5f * (float)KCODES) * Ntot;
    ws[W_NEWM + k] = sm;
    out[O_MM + k] = sm;
    if (k == 0) out[O_LOSS] = 0.25f * ws[W_LOSS] / (float)((size_t)NPTS * DIM);
}

__global__ void finalizeB(const float* __restrict__ emam,
                          float* __restrict__ out, const float* __restrict__ ws)
{
    int i = blockIdx.x * blockDim.x + threadIdx.x;
    int k = i >> 6;
    float nm = 0.99f * emam[i] + 0.01f * ws[W_DM + i];
    out[O_M + i] = nm;
    out[O_EMB + i] = nm / ws[W_NEWM + k];
}

extern "C" void kernel_launch(void* const* d_in, const int* in_sizes, int n_in,
                              void* d_out, int out_size, void* d_ws, size_t ws_size,
                              hipStream_t stream)
{
    const float* enc  = (const float*)d_in[0];
    const float* emb  = (const float*)d_in[1];
    const float* emam = (const float*)d_in[2];
    const float* emaM = (const float*)d_in[3];
    float* out = (float*)d_out;
    float* ws  = (float*)d_ws;

    hipMemsetAsync(ws, 0, (size_t)W_TOTAL * sizeof(float), stream);
    cnorm_kernel<<<2, 256, 0, stream>>>(emb, ws);
    assign_kernel<<<NPTS/128, 256, 0, stream>>>(enc, emb, out, ws);   // 1024 blocks
    scatter_kernel<<<256, 512, 0, stream>>>(enc, emb, out, ws);
    finalizeA<<<1, 512, 0, stream>>>(emaM, out, ws);
    finalizeB<<<(KCODES*DIM)/256, 256, 0, stream>>>(emam, out, ws);
}